// Round 13
// baseline (47.228 us; speedup 1.0000x reference)
//
#include <hip/hip_runtime.h>

typedef unsigned long long u64;
typedef unsigned int u32;

#define NB 64      // graphs
#define NN 128     // nodes per graph
#define NITER 5
#define NGEN 6     // initial labels + 5 WL iterations
#define SALT 0xD1B54A32D192ED03ULL
#define NPAIR_OFF (NB*(NB-1)/2)  // 2016 strict lower pairs
#define TSLOTS 256

__device__ __forceinline__ u64 mix64(u64 x) {
    u64 z = x + 0x9E3779B97F4A7C15ULL;
    z = (z ^ (z >> 30)) * 0xBF58476D1CE4E5B9ULL;
    z = (z ^ (z >> 27)) * 0x94D049BB133111EBULL;
    return z ^ (z >> 31);
}

// K1: WL chain, ONE WAVE PER GRAPH (64 blocks x 64 threads). Zero barriers,
// zero LDS. Lane owns nodes {lane, lane+64}; their 128-bit adjacency masks
// live in 4 VGPRs (packed via coalesced ballots). Neighbor feed g = mix(h^SALT)
// is pulled with __shfl (ds_bpermute reads the addressed lane's register
// independent of exec, and g0/g1 are computed by ALL lanes pre-divergence,
// so the divergent ctz-walk is safe). Idempotent.
__global__ __launch_bounds__(64) void wl_iter_wave(const float* __restrict__ adj,
                                                   const int* __restrict__ labels,
                                                   u64* __restrict__ hgen,
                                                   u32* __restrict__ KdiagU,
                                                   float* __restrict__ out) {
    const int b = blockIdx.x;
    const int lane = threadIdx.x;   // 0..63, block == wave

    // ---- pack adjacency via coalesced ballots ----
    const float* abase = adj + (size_t)b * NN * NN;
    u64 mA0 = 0, mA1 = 0, mB0 = 0, mB1 = 0;   // rows lane / lane+64, col halves
    #pragma unroll 8
    for (int k = 0; k < NN; ++k) {
        const float* arow = abase + (size_t)k * NN;
        const u64 m0 = __ballot(arow[lane] > 0.5f);
        const u64 m1 = __ballot(arow[64 + lane] > 0.5f);
        if (k == lane)      { mA0 = m0; mA1 = m1; }
        if (k == lane + 64) { mB0 = m0; mB1 = m1; }
    }

    u64 h0 = mix64((u64)(u32)labels[b * NN + lane]);
    u64 h1 = mix64((u64)(u32)labels[b * NN + 64 + lane]);
    u64* hg = hgen + (size_t)b * (NGEN * NN);
    hg[lane] = h0;
    hg[64 + lane] = h1;

    for (int it = 0; it < NITER; ++it) {
        const u64 g0 = mix64(h0 ^ SALT);   // all lanes compute (pre-divergence)
        const u64 g1 = mix64(h1 ^ SALT);
        u64 s0 = 0, s1 = 0, m;
        m = mA0; while (m) { int j = __builtin_ctzll(m); m &= m - 1; s0 += (u64)__shfl((long long)g0, j); }
        m = mA1; while (m) { int j = __builtin_ctzll(m); m &= m - 1; s0 += (u64)__shfl((long long)g1, j); }
        m = mB0; while (m) { int j = __builtin_ctzll(m); m &= m - 1; s1 += (u64)__shfl((long long)g0, j); }
        m = mB1; while (m) { int j = __builtin_ctzll(m); m &= m - 1; s1 += (u64)__shfl((long long)g1, j); }
        h0 = mix64(mix64(h0) + s0);
        h1 = mix64(mix64(h1) + s1);
        hg += NN;
        hg[lane] = h0;
        hg[64 + lane] = h1;
    }

    if (lane == 0) { KdiagU[b] = 0u; out[b * NB + b] = 1.0f; }
}

// K2: per-(graph,generation) hash table build — 384 independent blocks
// (R7 verbatim). Exports SoA keys/counts; accumulates Kdiag[b] = sum cnt^2.
__global__ __launch_bounds__(128) void wl_tables(const u64* __restrict__ hgen,
                                                 u64* __restrict__ keysg,
                                                 u32* __restrict__ cntsg,
                                                 u32* __restrict__ KdiagU) {
    const int bg = blockIdx.x;   // b*NGEN + gen
    const int t = threadIdx.x;

    __shared__ u64 keys[TSLOTS];
    __shared__ u32 cnts[TSLOTS];
    keys[t] = 0ULL; keys[t + 128] = 0ULL;
    cnts[t] = 0u;   cnts[t + 128] = 0u;
    __syncthreads();

    const u64 h = hgen[(size_t)bg * NN + t];
    u32 s = (u32)h & (TSLOTS - 1);
    for (;;) {
        u64 old = atomicCAS((unsigned long long*)&keys[s], 0ULL, h);
        if (old == 0ULL || old == h) { atomicAdd(&cnts[s], 1u); break; }
        s = (s + 1) & (TSLOTS - 1);
    }
    __syncthreads();

    u32 acc;
    {
        const u64 k0 = keys[t], k1 = keys[t + 128];
        const u32 c0 = cnts[t], c1 = cnts[t + 128];
        keysg[(size_t)bg * TSLOTS + t]       = k0;
        keysg[(size_t)bg * TSLOTS + t + 128] = k1;
        cntsg[(size_t)bg * TSLOTS + t]       = c0;
        cntsg[(size_t)bg * TSLOTS + t + 128] = c1;
        acc = c0 * c0 + c1 * c1;
    }
    #pragma unroll
    for (int off = 32; off > 0; off >>= 1) acc += __shfl_down(acc, off);
    __shared__ u32 part[2];
    if ((t & 63) == 0) part[t >> 6] = acc;
    __syncthreads();
    if (t == 0) atomicAdd(&KdiagU[bg / NGEN], part[0] + part[1]);
}

// K3: one block per strict lower pair (b1>b2), 256 threads (R7 verbatim).
// Stage b2's 6 tables (SoA, 18 KiB), probe with b1's 768 labels, normalize.
__global__ __launch_bounds__(256) void wl_pairs(const u64* __restrict__ hgen,
                                                const u64* __restrict__ keysg,
                                                const u32* __restrict__ cntsg,
                                                const u32* __restrict__ KdiagU,
                                                float* __restrict__ out) {
    const int p = blockIdx.x;
    int b1 = (int)((1.0f + sqrtf(1.0f + 8.0f * (float)p)) * 0.5f);
    while (b1 * (b1 - 1) / 2 > p) --b1;
    while ((b1 + 1) * b1 / 2 <= p) ++b1;
    const int b2 = p - b1 * (b1 - 1) / 2;

    const int t = threadIdx.x;
    __shared__ u64 keys[NGEN * TSLOTS];  // 12 KiB
    __shared__ u32 cnts[NGEN * TSLOTS];  // 6 KiB

    {   // keys: 768 x ulonglong2 over 256 threads
        const ulonglong2* src = (const ulonglong2*)(keysg + (size_t)b2 * NGEN * TSLOTS);
        ulonglong2* dst = (ulonglong2*)keys;
        #pragma unroll
        for (int k = 0; k < 3; ++k) dst[t + 256 * k] = src[t + 256 * k];
    }
    {   // counts: 384 x uint4 over 256 threads
        const uint4* src = (const uint4*)(cntsg + (size_t)b2 * NGEN * TSLOTS);
        uint4* dst = (uint4*)cnts;
        #pragma unroll
        for (int k = 0; k < 2; ++k) {
            const int idx = t + 256 * k;
            if (idx < 384) dst[idx] = src[idx];
        }
    }
    __syncthreads();

    u32 c = 0;
    const u64* abase = hgen + (size_t)b1 * NGEN * NN;
    #pragma unroll
    for (int k = 0; k < 3; ++k) {
        const int idx = t + 256 * k;        // 0..767 -> gen = idx>>7
        const u64 a = abase[idx];
        const int base = (idx >> 7) * TSLOTS;
        u32 s = (u32)a & (TSLOTS - 1);
        for (;;) {
            const u64 kk = keys[base + s];
            if (kk == a) { c += cnts[base + s]; break; }
            if (kk == 0ULL) break;
            s = (s + 1) & (TSLOTS - 1);
        }
    }

    #pragma unroll
    for (int off = 32; off > 0; off >>= 1) c += __shfl_down(c, off);
    __shared__ u32 part[4];
    if ((t & 63) == 0) part[t >> 6] = c;
    __syncthreads();
    if (t == 0) {
        const float v = (float)(part[0] + part[1] + part[2] + part[3])
                      / (sqrtf((float)KdiagU[b1]) * sqrtf((float)KdiagU[b2]));
        out[b1 * NB + b2] = v;
        out[b2 * NB + b1] = v;
    }
}

extern "C" void kernel_launch(void* const* d_in, const int* in_sizes, int n_in,
                              void* d_out, int out_size, void* d_ws, size_t ws_size,
                              hipStream_t stream) {
    const float* adj   = (const float*)d_in[0];   // [64,128,128] fp32 (0/1)
    const int*  labels = (const int*)d_in[1];     // [64,128] int32
    float* out = (float*)d_out;                   // [64,64] fp32

    char* ws = (char*)d_ws;
    u64* hgen   = (u64*)ws;                        // 64*768*8  = 384 KiB
    u32* KdiagU = (u32*)(ws + 448 * 1024);         // 256 B
    u64* keysg  = (u64*)(ws + 512 * 1024);         // 384*256*8 = 768 KiB
    u32* cntsg  = (u32*)(ws + 1536 * 1024);        // 384*256*4 = 384 KiB

    wl_iter_wave<<<NB, 64, 0, stream>>>(adj, labels, hgen, KdiagU, out);
    wl_tables   <<<NB * NGEN, 128, 0, stream>>>(hgen, keysg, cntsg, KdiagU);
    wl_pairs    <<<NPAIR_OFF, 256, 0, stream>>>(hgen, keysg, cntsg, KdiagU, out);
}